// Round 1
// baseline (257.556 us; speedup 1.0000x reference)
//
#include <hip/hip_runtime.h>
#include <stdint.h>
#include <math.h>

typedef unsigned int u32;
typedef unsigned long long u64;

#define BB 8
#define AA 19206
#define CCH 91
#define NCLS 90
#define KSEL 256
#define MAXDET 100
#define NROWS (BB*NCLS)      // 720
#define NFLAT (NCLS*MAXDET)  // 9000
#define IOU_T 0.6f

// ---------------- decode ----------------
__global__ void __launch_bounds__(256) k_decode(const float* __restrict__ enc,
    const float* __restrict__ anch, float* __restrict__ dec) {
  int i = blockIdx.x * 256 + threadIdx.x;
  if (i >= BB * AA) return;
  int a = i % AA;
  float4 e  = ((const float4*)enc)[i];
  float4 an = ((const float4*)anch)[a];
  float ty = e.x / 10.0f, tx = e.y / 10.0f, th = e.z / 5.0f, tw = e.w / 5.0f;
  float yc = ty * an.z + an.x;
  float xc = tx * an.w + an.y;
  float h  = expf(th) * an.z;
  float w  = expf(tw) * an.w;
  float4 o;
  o.x = yc - h * 0.5f; o.y = xc - w * 0.5f; o.z = yc + h * 0.5f; o.w = xc + w * 0.5f;
  ((float4*)dec)[i] = o;
}

// ---------------- sigmoid + transpose ----------------
#define ATILE 64
__global__ void __launch_bounds__(256) k_sigT(const float* __restrict__ logits,
                                              float* __restrict__ sc) {
  __shared__ float tile[ATILE * CCH];  // 23.3 KB
  int b  = blockIdx.y;
  int a0 = blockIdx.x * ATILE;
  int nt = AA - a0; if (nt > ATILE) nt = ATILE;
  int nload = nt * CCH;
  const float* src = logits + ((size_t)b * AA + a0) * CCH;
  for (int i = threadIdx.x; i < nload; i += 256) tile[i] = src[i];
  __syncthreads();
  for (int j = threadIdx.x; j < ATILE * NCLS; j += 256) {
    int c  = j >> 6;       // 0..89
    int ai = j & 63;
    if (ai < nt) {
      float x = tile[ai * CCH + (c + 1)];
      float s = 1.0f / (1.0f + expf(-x));
      sc[((size_t)b * NCLS + c) * AA + a0 + ai] = s;
    }
  }
}

// ---------------- bitonic sorts (block of 256 threads) ----------------
__device__ inline void bitonic_u64_asc(u64* a, int n, int tid) {
  for (int k = 2; k <= n; k <<= 1) {
    for (int j = k >> 1; j > 0; j >>= 1) {
      for (int i = tid; i < n; i += 256) {
        int l = i ^ j;
        if (l > i) {
          u64 x = a[i], y = a[l];
          bool asc = ((i & k) == 0);
          if ((x > y) == asc) { a[i] = y; a[l] = x; }
        }
      }
      __syncthreads();
    }
  }
}
__device__ inline void bitonic_u32_asc(u32* a, int n, int tid) {
  for (int k = 2; k <= n; k <<= 1) {
    for (int j = k >> 1; j > 0; j >>= 1) {
      for (int i = tid; i < n; i += 256) {
        int l = i ^ j;
        if (l > i) {
          u32 x = a[i], y = a[l];
          bool asc = ((i & k) == 0);
          if ((x > y) == asc) { a[i] = y; a[l] = x; }
        }
      }
      __syncthreads();
    }
  }
}

// ---------------- exact radix select (rank kwant, descending) ----------------
// Finds V = bits of the kwant-th largest value, GT = #elements strictly > V,
// r = kwant - GT = #elements == V to take (lowest indices).
// Values must be non-negative floats (bit order == value order).
template<typename F>
__device__ inline void radix_select(F getv, int n, int kwant,
    u32* hist, u32* suf, int* sh2, int tid,
    u32& V_out, int& GT_out, int& r_out) {
  int r = kwant; u32 V = 0; int GT = 0;
  for (int lvl = 0; lvl < 3; lvl++) {
    int shift = (lvl == 0) ? 19 : ((lvl == 1) ? 8 : 0);
    int nbins = (lvl == 2) ? 256 : 2048;
    for (int i = tid; i < nbins; i += 256) hist[i] = 0;
    __syncthreads();
    for (int idx = tid; idx < n; idx += 256) {
      u32 u = __float_as_uint(getv(idx));
      bool ok = (lvl == 0) || (lvl == 1 ? ((u >> 19) == (V >> 19))
                                        : ((u >> 8)  == (V >> 8)));
      if (ok) atomicAdd(&hist[(u >> shift) & (u32)(nbins - 1)], 1u);
    }
    __syncthreads();
    int G = nbins >> 8;
    u32 ps = 0;
    for (int g = 0; g < G; g++) ps += hist[tid * G + g];
    suf[tid] = ps;
    __syncthreads();
    for (int off = 1; off < 256; off <<= 1) {
      u32 v = (tid + off < 256) ? suf[tid + off] : 0u;
      __syncthreads();
      suf[tid] += v;
      __syncthreads();
    }
    u32 sufnext = (tid < 255) ? suf[tid + 1] : 0u;
    if (suf[tid] >= (u32)r && sufnext < (u32)r) {
      u32 cum = sufnext; int kb = tid * G;
      for (int bin = tid * G + G - 1; bin >= tid * G; bin--) {
        cum += hist[bin];
        if (cum >= (u32)r) { kb = bin; break; }
      }
      sh2[0] = kb;
      sh2[1] = (int)(cum - hist[kb]);
    }
    __syncthreads();
    int kb = sh2[0], gt = sh2[1];
    r -= gt; GT += gt; V |= ((u32)kb) << shift;
    __syncthreads();
  }
  V_out = V; GT_out = GT; r_out = r;
}

// ---------------- per-row top-256 ----------------
template<bool DIRECT>
__global__ void __launch_bounds__(256) k_topk(const float* __restrict__ src,
    float* __restrict__ tks, int* __restrict__ tki) {
  __shared__ u32 hist[2048];
  __shared__ u32 suf[256];
  __shared__ int sh2[2];
  __shared__ u64 sel[KSEL];
  __shared__ u32 tie[512];
  __shared__ int cgt, ctie;
  int row = blockIdx.x, tid = threadIdx.x;
  int b = row / NCLS, c = row % NCLS;
  const float* base = DIRECT ? (src + (size_t)b * AA * CCH + (c + 1))
                             : (src + (size_t)row * AA);
  auto getv = [&](int i) -> float {
    if (DIRECT) { float x = base[(size_t)i * CCH]; return 1.0f / (1.0f + expf(-x)); }
    return base[i];
  };
  u32 V; int GT, r;
  radix_select(getv, AA, KSEL, hist, suf, sh2, tid, V, GT, r);
  if (tid == 0) { cgt = 0; ctie = 0; }
  __syncthreads();
  for (int i = tid; i < AA; i += 256) {
    u32 u = __float_as_uint(getv(i));
    if (u > V) {
      int p = atomicAdd(&cgt, 1);
      sel[p] = ((u64)u << 32) | (u32)(~(u32)i);
    } else if (u == V) {
      int p = atomicAdd(&ctie, 1);
      if (p < 512) tie[p] = (u32)i;
    }
  }
  __syncthreads();
  int nt = ctie < 512 ? ctie : 512;
  for (int i = tid + nt; i < 512; i += 256) tie[i] = 0xFFFFFFFFu;
  __syncthreads();
  bitonic_u32_asc(tie, 512, tid);           // ascending original index
  for (int i = tid; i < r; i += 256)
    sel[GT + i] = ((u64)V << 32) | (u32)(~tie[i]);
  __syncthreads();
  bitonic_u64_asc(sel, KSEL, tid);          // ascending; rank j = sel[255-j]
  for (int j = tid; j < KSEL; j += 256) {
    u64 kk = sel[KSEL - 1 - j];
    tks[(size_t)row * KSEL + j] = __uint_as_float((u32)(kk >> 32));
    tki[(size_t)row * KSEL + j] = (int)(~(u32)kk);
  }
}

// ---------------- NMS: one wave per (b,c) row ----------------
__global__ void __launch_bounds__(256) k_nms(const float* __restrict__ dec,
    const float* __restrict__ tks, const int* __restrict__ tki,
    float* __restrict__ flat_s, float* __restrict__ flat_b) {
  __shared__ float4 bxs[4][KSEL];   // 16 KB
  int wid = threadIdx.x >> 6, lane = threadIdx.x & 63;
  int row = blockIdx.x * 4 + wid;
  int b = row / NCLS, c = row % NCLS;
  float  s[4]; float4 bx[4]; float ar[4];
  for (int k = 0; k < 4; k++) {
    int j = lane + 64 * k;
    s[k] = tks[(size_t)row * KSEL + j];
    int ai = tki[(size_t)row * KSEL + j];
    float4 bb = ((const float4*)dec)[(size_t)b * AA + ai];
    bx[k] = bb;
    ar[k] = (bb.z - bb.x) * (bb.w - bb.y);
    bxs[wid][j] = bb;
  }
  __syncthreads();
  for (int d = 0; d < MAXDET; d++) {
    // argmax over 256 current scores, tie -> lowest list position
    u64 best = 0;
    for (int k = 0; k < 4; k++) {
      u32 ub = __float_as_uint(s[k]);
      u32 mu = (ub & 0x80000000u) ? ~ub : (ub | 0x80000000u);  // monotone map
      best = max(best, (((u64)mu << 32) | (u32)(255 - (lane + 64 * k))));
    }
    for (int off = 1; off < 64; off <<= 1) {
      u64 o = __shfl_xor(best, off);
      best = max(best, o);
    }
    int i  = 255 - (int)(best & 0xFFu);
    u32 mu = (u32)(best >> 32);
    u32 ub = (mu & 0x80000000u) ? (mu & 0x7FFFFFFFu) : ~mu;
    float val = __uint_as_float(ub);
    bool keep = val > 0.0f;
    float4 bi = bxs[wid][i];                 // broadcast read
    float ia  = (bi.z - bi.x) * (bi.w - bi.y);
    if (lane == 0) {
      size_t fo = (size_t)b * NFLAT + (size_t)c * MAXDET + d;
      flat_s[fo] = keep ? val : 0.0f;
      float4 ob;
      if (keep) ob = bi; else { ob.x = ob.y = ob.z = ob.w = 0.0f; }
      ((float4*)flat_b)[fo] = ob;
    }
    for (int k = 0; k < 4; k++) {
      float ty = fmaxf(bi.x, bx[k].x), tx = fmaxf(bi.y, bx[k].y);
      float by = fminf(bi.z, bx[k].z), bxx = fminf(bi.w, bx[k].w);
      float wy = fmaxf(by - ty, 0.0f), wx = fmaxf(bxx - tx, 0.0f);
      float inter = wy * wx;
      float un = ia + ar[k] - inter;
      float iou = inter / fmaxf(un, 1e-8f);
      if (iou >= IOU_T) s[k] = -1.0f;
    }
  }
}

// ---------------- final per-batch top-100 ----------------
__global__ void __launch_bounds__(256) k_final(const float* __restrict__ flat_s,
    const float* __restrict__ flat_b, float* __restrict__ out) {
  __shared__ u32 hist[2048];
  __shared__ u32 suf[256];
  __shared__ int sh2[2];
  __shared__ u64 sel[128];
  __shared__ u32 tie[256];
  __shared__ int cgt, ctie;
  int b = blockIdx.x, tid = threadIdx.x;
  const float* data = flat_s + (size_t)b * NFLAT;
  auto getv = [&](int i) -> float { return data[i]; };
  u32 V; int GT, r;
  radix_select(getv, NFLAT, MAXDET, hist, suf, sh2, tid, V, GT, r);
  if (tid == 0) { cgt = 0; ctie = 0; }
  __syncthreads();
  for (int i = tid; i < NFLAT; i += 256) {
    u32 u = __float_as_uint(data[i]);
    if (u > V) {
      int p = atomicAdd(&cgt, 1);
      sel[p] = ((u64)u << 32) | (u32)(~(u32)i);
    } else if (u == V) {
      int p = atomicAdd(&ctie, 1);
      if (p < 256) tie[p] = (u32)i;
    }
  }
  __syncthreads();
  int nt = ctie < 256 ? ctie : 256;
  for (int i = tid + nt; i < 256; i += 256) tie[i] = 0xFFFFFFFFu;
  __syncthreads();
  bitonic_u32_asc(tie, 256, tid);
  for (int i = tid; i < r; i += 256)
    sel[GT + i] = ((u64)V << 32) | (u32)(~tie[i]);
  for (int i = MAXDET + tid; i < 128; i += 256) sel[i] = 0;
  __syncthreads();
  bitonic_u64_asc(sel, 128, tid);
  for (int d = tid; d < MAXDET; d += 256) {
    u64 kk = sel[127 - d];
    u32 u  = (u32)(kk >> 32);
    int fi = (int)(~(u32)kk);
    float4 bb = ((const float4*)flat_b)[(size_t)b * NFLAT + fi];
    float* o = out + ((size_t)b * MAXDET + d) * 6;
    o[0] = bb.x; o[1] = bb.y; o[2] = bb.z; o[3] = bb.w;
    o[4] = (float)(fi / 100 + 1);
    o[5] = __uint_as_float(u);
  }
}

// ---------------- launch ----------------
extern "C" void kernel_launch(void* const* d_in, const int* in_sizes, int n_in,
                              void* d_out, int out_size, void* d_ws, size_t ws_size,
                              hipStream_t stream) {
  const float* enc    = (const float*)d_in[0];
  const float* logits = (const float*)d_in[1];
  const float* anch   = (const float*)d_in[2];
  float* out = (float*)d_out;
  char* ws = (char*)d_ws;

  size_t off = 0;
  auto alloc = [&](size_t bytes) {
    size_t o = off;
    off += (bytes + 255) & ~(size_t)255;
    return o;
  };
  size_t o_dec = alloc((size_t)BB * AA * 16);          // decoded boxes (float4)
  size_t o_tks = alloc((size_t)NROWS * KSEL * 4);      // top-k scores
  size_t o_tki = alloc((size_t)NROWS * KSEL * 4);      // top-k indices
  size_t o_fls = alloc((size_t)BB * NFLAT * 4);        // flat scores
  size_t o_flb = alloc((size_t)BB * NFLAT * 16);       // flat boxes (float4)
  size_t need_base = off;
  size_t o_sc  = alloc((size_t)BB * NCLS * AA * 4);    // transposed sigmoid scores
  size_t need_full = off;
  (void)need_base;

  bool use_sc = (ws_size >= need_full);

  float* dec = (float*)(ws + o_dec);
  float* tks = (float*)(ws + o_tks);
  int*   tki = (int*)  (ws + o_tki);
  float* fls = (float*)(ws + o_fls);
  float* flb = (float*)(ws + o_flb);
  float* scp = (float*)(ws + o_sc);

  hipLaunchKernelGGL(k_decode, dim3((BB * AA + 255) / 256), dim3(256), 0, stream,
                     enc, anch, dec);
  if (use_sc) {
    hipLaunchKernelGGL(k_sigT, dim3((AA + ATILE - 1) / ATILE, BB), dim3(256), 0, stream,
                       logits, scp);
    hipLaunchKernelGGL((k_topk<false>), dim3(NROWS), dim3(256), 0, stream,
                       scp, tks, tki);
  } else {
    hipLaunchKernelGGL((k_topk<true>), dim3(NROWS), dim3(256), 0, stream,
                       logits, tks, tki);
  }
  hipLaunchKernelGGL(k_nms, dim3(NROWS / 4), dim3(256), 0, stream,
                     dec, tks, tki, fls, flb);
  hipLaunchKernelGGL(k_final, dim3(BB), dim3(256), 0, stream,
                     fls, flb, out);
}